// Round 4
// baseline (120.814 us; speedup 1.0000x reference)
//
#include <hip/hip_runtime.h>

#ifndef __has_builtin
#define __has_builtin(x) 0
#endif
#if __has_builtin(__builtin_amdgcn_exp2f)
#define EXP2F(x) __builtin_amdgcn_exp2f(x)
#else
#define EXP2F(x) exp2f(x)
#endif

namespace {

constexpr int T = 4096;
constexpr int C = 128;
constexpr int H = 8;
constexpr int D = 16;
constexpr int BH = 16;                         // B*H
constexpr size_t PLANE = (size_t)BH * T * D;   // 1,048,576 elements per tensor

using bf16x8 = __attribute__((ext_vector_type(8))) short;
using u16x4  = __attribute__((ext_vector_type(4))) unsigned short;
using f32x16 = __attribute__((ext_vector_type(16))) float;

__device__ __forceinline__ uint32_t cvt_pk_bf16(float lo, float hi) {
  uint32_t r;
  asm volatile("v_cvt_pk_bf16_f32 %0, %1, %2" : "=v"(r) : "v"(lo), "v"(hi));
  return r;
}

// ---------------------------------------------------------------------------
// Kernel 1: QKV projection -> bf16 (coalesced stores via LDS repack).
//   Qbf[bh][t][d] (pre-scaled by D^-1/2*log2e), Kbf[bh][t][d], Vt[bh][d][t].
// ---------------------------------------------------------------------------
__global__ __launch_bounds__(256) void qkv_proj(
    const float* __restrict__ x, const float* __restrict__ Wq,
    const float* __restrict__ Wk, const float* __restrict__ Wv,
    unsigned short* __restrict__ Qbf, unsigned short* __restrict__ Kbf,
    unsigned short* __restrict__ Vt) {
  __shared__ float Xs[128][68];  // [k][m]
  __shared__ float Ws[128][68];  // [k][n]
  const int tid = threadIdx.x;
  const int bm = blockIdx.x;            // 128 row blocks
  const int bn = blockIdx.y;            // 6 col blocks
  const int mat = bn >> 1;              // 0=Q 1=K 2=V
  const int c0 = (bn & 1) * 64;
  const float* W = (mat == 0) ? Wq : (mat == 1) ? Wk : Wv;
  const int t0 = bm * 64;

  const float4* xsrc = (const float4*)(x + (size_t)t0 * C);
  const float4* wsrc = (const float4*)(W + (size_t)c0 * C);
  for (int f = tid; f < 2048; f += 256) {
    const int m = f >> 5, k = (f & 31) << 2;
    float4 v = xsrc[f];
    Xs[k + 0][m] = v.x; Xs[k + 1][m] = v.y; Xs[k + 2][m] = v.z; Xs[k + 3][m] = v.w;
    float4 u = wsrc[f];
    Ws[k + 0][m] = u.x; Ws[k + 1][m] = u.y; Ws[k + 2][m] = u.z; Ws[k + 3][m] = u.w;
  }
  __syncthreads();

  const int tx = tid & 15, ty = tid >> 4;
  float acc[4][4] = {};
#pragma unroll 8
  for (int k = 0; k < 128; ++k) {
    const float4 a = *(const float4*)&Xs[k][ty * 4];
    const float4 b = *(const float4*)&Ws[k][tx * 4];
    const float av[4] = {a.x, a.y, a.z, a.w};
    const float bv[4] = {b.x, b.y, b.z, b.w};
#pragma unroll
    for (int i = 0; i < 4; ++i)
#pragma unroll
      for (int j = 0; j < 4; ++j) acc[i][j] = fmaf(av[i], bv[j], acc[i][j]);
  }
  __syncthreads();  // done reading Xs -> reuse as bf16 staging

  unsigned short* Ls = (unsigned short*)&Xs[0][0];  // [64][72] bf16
  if (mat < 2) {
    const float sc = (mat == 0) ? 0.25f * 1.4426950408889634f : 1.0f;
#pragma unroll
    for (int i = 0; i < 4; ++i) {                 // Ls[t][c] packed bf16
      const uint32_t u0 = cvt_pk_bf16(acc[i][0] * sc, acc[i][1] * sc);
      const uint32_t u1 = cvt_pk_bf16(acc[i][2] * sc, acc[i][3] * sc);
      *(uint32_t*)&Ls[(ty * 4 + i) * 72 + tx * 4]     = u0;
      *(uint32_t*)&Ls[(ty * 4 + i) * 72 + tx * 4 + 2] = u1;
    }
    __syncthreads();
    unsigned short* dst = (mat == 0) ? Qbf : Kbf;
    const int lane = tid & 63, hp = tid >> 6;     // wave hp -> head-slot hp
    const int tr = t0 + lane, b = tr >> 12, t = tr & (T - 1);
    const int head = (c0 >> 4) + hp;
    unsigned short* base = dst + (((size_t)(b * H + head)) * T + t) * D;
#pragma unroll
    for (int p = 0; p < 2; ++p)                   // 2x16B per lane, coalesced
      *(uint4*)(base + p * 8) = *(const uint4*)&Ls[lane * 72 + hp * 16 + p * 8];
  } else {
#pragma unroll
    for (int j = 0; j < 4; ++j) {                 // Ls[c][t] (transposed)
      const uint32_t u0 = cvt_pk_bf16(acc[0][j], acc[1][j]);
      const uint32_t u1 = cvt_pk_bf16(acc[2][j], acc[3][j]);
      *(uint32_t*)&Ls[(tx * 4 + j) * 72 + ty * 4]     = u0;
      *(uint32_t*)&Ls[(tx * 4 + j) * 72 + ty * 4 + 2] = u1;
    }
    __syncthreads();
    const int c = tid >> 2;                       // 0..63
    const int b = t0 >> 12;
    const int head = (c0 + c) >> 4, dvv = (c0 + c) & 15;
    unsigned short* base =
        Vt + (((size_t)(b * H + head)) * D + dvv) * T + (t0 & (T - 1));
#pragma unroll
    for (int it = 0; it < 2; ++it) {
      const int part = (tid & 3) + 4 * it;
      *(uint4*)(base + part * 8) = *(const uint4*)&Ls[c * 72 + part * 8];
    }
  }
}

// ---------------------------------------------------------------------------
// Kernel 2: causal flash attention, 32x32x16 bf16 MFMA, paired-tile blocks.
// Block = 8 waves (512 thr) owning q-tile pair (127-j, j): exactly 129
// key-steps per block -> all 1024 blocks equal duration, 4 blocks/CU all
// resident (VGPR<=64 via launch_bounds, LDS 38.9KB*4 = 155.6KB <= 160KB).
// Wave w takes combined steps i == w (mod 8): its tile-A steps, then tile-B.
// Per-phase partials (m, l, acc rows 0..15) dumped to LDS; waves 0/1 merge.
// bh->XCD-affine block map keeps each XCD's K/V working set ~512KB (L2-fit).
// ---------------------------------------------------------------------------
__global__ __launch_bounds__(512, 8) void attn_fwd(
    const unsigned short* __restrict__ Qbf, const unsigned short* __restrict__ Kbf,
    const unsigned short* __restrict__ Vt, float* __restrict__ att) {
  __shared__ float Pm[2][8][32];
  __shared__ float Pl[2][8][32];
  __shared__ float Po[2][8][32][17];
  const int tid = threadIdx.x;
  const int w = tid >> 6, l = tid & 63;
  const int lane31 = l & 31, h = l >> 5, dv = l & 15;
  const int ib = blockIdx.x;
  const int bh = 2 * (ib & 7) + ((ib >> 3) & 1);  // XCD x <- bh {2x, 2x+1}
  const int pj = ib >> 4;                         // 0..63
  const int tileA = 127 - pj, tileB = pj;
  const int nsA = tileA + 1, nsB = tileB + 1;     // nsA >= 65 > 8 always

  const unsigned short* Qp = Qbf + (size_t)bh * T * D;
  const unsigned short* Kp = Kbf + (size_t)bh * T * D;
  const unsigned short* Vp = Vt + (size_t)bh * D * T;

  auto run_phase = [&](int tile, int s0, int ns, int slot) {
    const int qidx = tile * 32 + lane31;
    const bf16x8 qf = *(const bf16x8*)(Qp + (size_t)qidx * D + 8 * h);
    float m = -1e30f, lsum = 0.f;       // first step triggers alpha=0 rescale
    f32x16 acc = {};
#pragma unroll 1
    for (int s = s0; s < ns; s += 8) {
      const int k0 = s * 32;
      const bf16x8 kf = *(const bf16x8*)(Kp + (size_t)(k0 + lane31) * D + 8 * h);
      const unsigned short* vb = Vp + (size_t)dv * T + k0 + 4 * h;
      const u16x4 v0 = *(const u16x4*)(vb);
      const u16x4 v1 = *(const u16x4*)(vb + 8);
      const u16x4 v2 = *(const u16x4*)(vb + 16);
      const u16x4 v3 = *(const u16x4*)(vb + 24);

      f32x16 s16 = {};
      __builtin_amdgcn_s_setprio(1);
      s16 = __builtin_amdgcn_mfma_f32_32x32x16_bf16(kf, qf, s16, 0, 0, 0);
      __builtin_amdgcn_s_setprio(0);

      if (s == tile) {                  // diagonal step: causal mask
#pragma unroll
        for (int r = 0; r < 16; ++r) {
          const int key = k0 + (r & 3) + 8 * (r >> 2) + 4 * h;
          if (key > qidx) s16[r] = -1e30f;
        }
      }

      // max tree in 3-ary groups (v_max3-fusable)
      const float t0 = fmaxf(fmaxf(s16[0], s16[1]), s16[2]);
      const float t1 = fmaxf(fmaxf(s16[3], s16[4]), s16[5]);
      const float t2 = fmaxf(fmaxf(s16[6], s16[7]), s16[8]);
      const float t3 = fmaxf(fmaxf(s16[9], s16[10]), s16[11]);
      const float t4 = fmaxf(fmaxf(s16[12], s16[13]), s16[14]);
      const float u0 = fmaxf(fmaxf(t0, t1), t2);
      const float u1 = fmaxf(fmaxf(t3, t4), s16[15]);
      const float lm = fmaxf(u0, u1);

      if (!__all(lm <= m + 8.f)) {      // rare (deferred-max); wave-uniform
        const float tm = fmaxf(lm, __shfl_xor(lm, 32, 64));
        const float mn = fmaxf(m, tm);
        const float alpha = EXP2F(m - mn);
        lsum *= alpha;
#pragma unroll
        for (int j = 0; j < 8; ++j) acc[j] *= alpha;
        m = mn;
      }

#pragma unroll
      for (int r = 0; r < 16; ++r) s16[r] = EXP2F(s16[r] - m);
      lsum += ((s16[0] + s16[1]) + (s16[2] + s16[3])) +
              ((s16[4] + s16[5]) + (s16[6] + s16[7])) +
              ((s16[8] + s16[9]) + (s16[10] + s16[11])) +
              ((s16[12] + s16[13]) + (s16[14] + s16[15]));

      union PF { bf16x8 v; uint32_t u[4]; } pa, pb;
      pa.u[0] = cvt_pk_bf16(s16[0], s16[1]);
      pa.u[1] = cvt_pk_bf16(s16[2], s16[3]);
      pa.u[2] = cvt_pk_bf16(s16[4], s16[5]);
      pa.u[3] = cvt_pk_bf16(s16[6], s16[7]);
      pb.u[0] = cvt_pk_bf16(s16[8], s16[9]);
      pb.u[1] = cvt_pk_bf16(s16[10], s16[11]);
      pb.u[2] = cvt_pk_bf16(s16[12], s16[13]);
      pb.u[3] = cvt_pk_bf16(s16[14], s16[15]);

      union VF { bf16x8 v; u16x4 q4[2]; } va, vb2;
      va.q4[0] = v0;  va.q4[1] = v1;    // keys k0+0..15  (slot fn = P's)
      vb2.q4[0] = v2; vb2.q4[1] = v3;   // keys k0+16..31
      __builtin_amdgcn_s_setprio(1);
      acc = __builtin_amdgcn_mfma_f32_32x32x16_bf16(va.v, pa.v, acc, 0, 0, 0);
      acc = __builtin_amdgcn_mfma_f32_32x32x16_bf16(vb2.v, pb.v, acc, 0, 0, 0);
      __builtin_amdgcn_s_setprio(0);
    }
    lsum += __shfl_xor(lsum, 32, 64);   // pair holds same q: combine halves
    Pm[slot][w][lane31] = m;
    Pl[slot][w][lane31] = lsum;
#pragma unroll
    for (int j = 0; j < 8; ++j) {
      const int dj = (j & 3) + 8 * (j >> 2) + 4 * h;
      Po[slot][w][lane31][dj] = acc[j];
    }
  };

  // phase A: steps i = w, w+8, ... while i < nsA  (s = i)
  run_phase(tileA, w, nsA, 0);
  // phase B: continue combined list; first B step = i_end - nsA
  const int cA = (nsA - w + 7) >> 3;
  const int sB0 = w + 8 * cA - nsA;
  run_phase(tileB, sB0, nsB, 1);

  __syncthreads();

  if (w < 2) {                          // wave 0 -> tile A, wave 1 -> tile B
    const int tile = (w == 0) ? tileA : tileB;
    const int qidx = tile * 32 + lane31;
    float M = Pm[w][0][lane31];
#pragma unroll
    for (int p = 1; p < 8; ++p) M = fmaxf(M, Pm[w][p][lane31]);
    float L = 0.f, od[8] = {};
#pragma unroll
    for (int p = 0; p < 8; ++p) {
      const float wsc = EXP2F(Pm[w][p][lane31] - M);  // -1e30 slots -> 0
      L = fmaf(Pl[w][p][lane31], wsc, L);
#pragma unroll
      for (int j = 0; j < 8; ++j) {
        const int dj = (j & 3) + 8 * (j >> 2) + 4 * h;
        od[j] = fmaf(Po[w][p][lane31][dj], wsc, od[j]);
      }
    }
    const float inv = 1.f / L;
    float* base = att + ((size_t)bh * T + qidx) * D;
    *(float4*)(base + 4 * h) =
        make_float4(od[0] * inv, od[1] * inv, od[2] * inv, od[3] * inv);
    *(float4*)(base + 8 + 4 * h) =
        make_float4(od[4] * inv, od[5] * inv, od[6] * inv, od[7] * inv);
  }
}

// ---------------------------------------------------------------------------
// Kernel 3: output projection + bias (fp32, unchanged).
// ---------------------------------------------------------------------------
__global__ __launch_bounds__(256) void out_proj(
    const float* __restrict__ att, const float* __restrict__ Wp,
    const float* __restrict__ bp, float* __restrict__ out) {
  __shared__ float As[128][68];
  __shared__ float Bs[128][68];
  const int tid = threadIdx.x;
  const int t0 = blockIdx.x * 64;
  const int c0 = blockIdx.y * 64;

  for (int f = tid; f < 2048; f += 256) {
    const int mm = f & 63;
    const int cp = (f >> 6) << 2;
    const int tr = t0 + mm;
    const int b = tr >> 12, t = tr & (T - 1);
    const int h = cp >> 4, d0 = cp & 15;
    const float4 v = *(const float4*)(att + (((size_t)b * H + h) * T + t) * D + d0);
    As[cp + 0][mm] = v.x; As[cp + 1][mm] = v.y; As[cp + 2][mm] = v.z; As[cp + 3][mm] = v.w;
  }
  const float4* wsrc = (const float4*)(Wp + (size_t)c0 * C);
  for (int f = tid; f < 2048; f += 256) {
    const float4 v = wsrc[f];
    const int n = f >> 5, k = (f & 31) << 2;
    Bs[k + 0][n] = v.x; Bs[k + 1][n] = v.y; Bs[k + 2][n] = v.z; Bs[k + 3][n] = v.w;
  }
  __syncthreads();

  const int tx = tid & 15, ty = tid >> 4;
  float acc[4][4] = {};
#pragma unroll 8
  for (int k = 0; k < 128; ++k) {
    const float4 a = *(const float4*)&As[k][ty * 4];
    const float4 b = *(const float4*)&Bs[k][tx * 4];
    const float av[4] = {a.x, a.y, a.z, a.w};
    const float bv[4] = {b.x, b.y, b.z, b.w};
#pragma unroll
    for (int i = 0; i < 4; ++i)
#pragma unroll
      for (int j = 0; j < 4; ++j) acc[i][j] = fmaf(av[i], bv[j], acc[i][j]);
  }

  const float4 bias = *(const float4*)(bp + c0 + tx * 4);
#pragma unroll
  for (int i = 0; i < 4; ++i) {
    const int tr = t0 + ty * 4 + i;
    const float4 v = make_float4(acc[i][0] + bias.x, acc[i][1] + bias.y,
                                 acc[i][2] + bias.z, acc[i][3] + bias.w);
    *(float4*)(out + (size_t)tr * C + c0 + tx * 4) = v;
  }
}

}  // namespace

extern "C" void kernel_launch(void* const* d_in, const int* in_sizes, int n_in,
                              void* d_out, int out_size, void* d_ws, size_t ws_size,
                              hipStream_t stream) {
  // setup_inputs order: x, Wk, Wq, Wv, Wp, bp
  const float* x  = (const float*)d_in[0];
  const float* Wk = (const float*)d_in[1];
  const float* Wq = (const float*)d_in[2];
  const float* Wv = (const float*)d_in[3];
  const float* Wp = (const float*)d_in[4];
  const float* bp = (const float*)d_in[5];

  float* att = (float*)d_ws;                             // 4 MiB fp32
  unsigned short* Qbf = (unsigned short*)(att + PLANE);  // 2 MiB bf16
  unsigned short* Kbf = Qbf + PLANE;                     // 2 MiB
  unsigned short* Vtb = Kbf + PLANE;                     // 2 MiB (10 MiB ws)

  qkv_proj<<<dim3(128, 6), 256, 0, stream>>>(x, Wq, Wk, Wv, Qbf, Kbf, Vtb);
  attn_fwd<<<dim3(1024), 512, 0, stream>>>(Qbf, Kbf, Vtb, att);
  out_proj<<<dim3(128, 2), 256, 0, stream>>>(att, Wp, bp, (float*)d_out);
}

// Round 5
// 101.909 us; speedup vs baseline: 1.1855x; 1.1855x over previous
//
#include <hip/hip_runtime.h>

#ifndef __has_builtin
#define __has_builtin(x) 0
#endif
#if __has_builtin(__builtin_amdgcn_exp2f)
#define EXP2F(x) __builtin_amdgcn_exp2f(x)
#else
#define EXP2F(x) exp2f(x)
#endif

namespace {

constexpr int T = 4096;
constexpr int C = 128;
constexpr int H = 8;
constexpr int D = 16;
constexpr int BH = 16;                         // B*H
constexpr size_t PLANE = (size_t)BH * T * D;   // 1,048,576 elements per tensor

using bf16x8 = __attribute__((ext_vector_type(8))) short;
using u16x4  = __attribute__((ext_vector_type(4))) unsigned short;
using f32x16 = __attribute__((ext_vector_type(16))) float;

__device__ __forceinline__ uint32_t cvt_pk_bf16(float lo, float hi) {
  uint32_t r;
  asm volatile("v_cvt_pk_bf16_f32 %0, %1, %2" : "=v"(r) : "v"(lo), "v"(hi));
  return r;
}

// ---------------------------------------------------------------------------
// Kernel 1: QKV projection -> bf16 (coalesced stores via LDS repack).
//   Qbf[bh][t][d] (pre-scaled by D^-1/2*log2e), Kbf[bh][t][d], Vt[bh][d][t].
// ---------------------------------------------------------------------------
__global__ __launch_bounds__(256) void qkv_proj(
    const float* __restrict__ x, const float* __restrict__ Wq,
    const float* __restrict__ Wk, const float* __restrict__ Wv,
    unsigned short* __restrict__ Qbf, unsigned short* __restrict__ Kbf,
    unsigned short* __restrict__ Vt) {
  __shared__ float Xs[128][68];  // [k][m]
  __shared__ float Ws[128][68];  // [k][n]
  const int tid = threadIdx.x;
  const int bm = blockIdx.x;            // 128 row blocks
  const int bn = blockIdx.y;            // 6 col blocks
  const int mat = bn >> 1;              // 0=Q 1=K 2=V
  const int c0 = (bn & 1) * 64;
  const float* W = (mat == 0) ? Wq : (mat == 1) ? Wk : Wv;
  const int t0 = bm * 64;

  const float4* xsrc = (const float4*)(x + (size_t)t0 * C);
  const float4* wsrc = (const float4*)(W + (size_t)c0 * C);
  for (int f = tid; f < 2048; f += 256) {
    const int m = f >> 5, k = (f & 31) << 2;
    float4 v = xsrc[f];
    Xs[k + 0][m] = v.x; Xs[k + 1][m] = v.y; Xs[k + 2][m] = v.z; Xs[k + 3][m] = v.w;
    float4 u = wsrc[f];
    Ws[k + 0][m] = u.x; Ws[k + 1][m] = u.y; Ws[k + 2][m] = u.z; Ws[k + 3][m] = u.w;
  }
  __syncthreads();

  const int tx = tid & 15, ty = tid >> 4;
  float acc[4][4] = {};
#pragma unroll 8
  for (int k = 0; k < 128; ++k) {
    const float4 a = *(const float4*)&Xs[k][ty * 4];
    const float4 b = *(const float4*)&Ws[k][tx * 4];
    const float av[4] = {a.x, a.y, a.z, a.w};
    const float bv[4] = {b.x, b.y, b.z, b.w};
#pragma unroll
    for (int i = 0; i < 4; ++i)
#pragma unroll
      for (int j = 0; j < 4; ++j) acc[i][j] = fmaf(av[i], bv[j], acc[i][j]);
  }
  __syncthreads();  // done reading Xs -> reuse as bf16 staging

  unsigned short* Ls = (unsigned short*)&Xs[0][0];  // [64][72] bf16
  if (mat < 2) {
    const float sc = (mat == 0) ? 0.25f * 1.4426950408889634f : 1.0f;
#pragma unroll
    for (int i = 0; i < 4; ++i) {                 // Ls[t][c] packed bf16
      const uint32_t u0 = cvt_pk_bf16(acc[i][0] * sc, acc[i][1] * sc);
      const uint32_t u1 = cvt_pk_bf16(acc[i][2] * sc, acc[i][3] * sc);
      *(uint32_t*)&Ls[(ty * 4 + i) * 72 + tx * 4]     = u0;
      *(uint32_t*)&Ls[(ty * 4 + i) * 72 + tx * 4 + 2] = u1;
    }
    __syncthreads();
    unsigned short* dst = (mat == 0) ? Qbf : Kbf;
    const int lane = tid & 63, hp = tid >> 6;     // wave hp -> head-slot hp
    const int tr = t0 + lane, b = tr >> 12, t = tr & (T - 1);
    const int head = (c0 >> 4) + hp;
    unsigned short* base = dst + (((size_t)(b * H + head)) * T + t) * D;
#pragma unroll
    for (int p = 0; p < 2; ++p)                   // 2x16B per lane, coalesced
      *(uint4*)(base + p * 8) = *(const uint4*)&Ls[lane * 72 + hp * 16 + p * 8];
  } else {
#pragma unroll
    for (int j = 0; j < 4; ++j) {                 // Ls[c][t] (transposed)
      const uint32_t u0 = cvt_pk_bf16(acc[0][j], acc[1][j]);
      const uint32_t u1 = cvt_pk_bf16(acc[2][j], acc[3][j]);
      *(uint32_t*)&Ls[(tx * 4 + j) * 72 + ty * 4]     = u0;
      *(uint32_t*)&Ls[(tx * 4 + j) * 72 + ty * 4 + 2] = u1;
    }
    __syncthreads();
    const int c = tid >> 2;                       // 0..63
    const int b = t0 >> 12;
    const int head = (c0 + c) >> 4, dvv = (c0 + c) & 15;
    unsigned short* base =
        Vt + (((size_t)(b * H + head)) * D + dvv) * T + (t0 & (T - 1));
#pragma unroll
    for (int it = 0; it < 2; ++it) {
      const int part = (tid & 3) + 4 * it;
      *(uint4*)(base + part * 8) = *(const uint4*)&Ls[c * 72 + part * 8];
    }
  }
}

// ---------------------------------------------------------------------------
// Kernel 2: causal flash attention, 32x32x16 bf16 MFMA, paired-tile blocks.
// Block = 4 waves (256 thr) owning q-tile pair (127-j, j): exactly 129
// key-steps -> 1024 equal-duration blocks = exactly 4/CU, all co-resident
// (LDS 19.5KB*4=78KB, VGPR cap 128 via launch_bounds -> NO spills; round-4's
// (512,8) cap forced VGPR=32 and 47MB of scratch writes = the regression).
// Wave w takes combined steps i == w (mod 4): tile-A steps then tile-B.
// Inner loop unrolled 2 steps (s, s+4): independent MFMA/exp2 chains share
// one deferred-max check; both K/V loads issue at iter top (latency overlap).
// Partials merged through LDS; waves 0/1 write the two tiles' outputs.
// ---------------------------------------------------------------------------
__global__ __launch_bounds__(256, 4) void attn_fwd(
    const unsigned short* __restrict__ Qbf, const unsigned short* __restrict__ Kbf,
    const unsigned short* __restrict__ Vt, float* __restrict__ att) {
  __shared__ float Pm[2][4][32];
  __shared__ float Pl[2][4][32];
  __shared__ float Po[2][4][32][17];
  const int tid = threadIdx.x;
  const int w = tid >> 6, l = tid & 63;
  const int lane31 = l & 31, h = l >> 5, dv = l & 15;
  const int ib = blockIdx.x;
  const int bh = 2 * (ib & 7) + ((ib >> 3) & 1);  // XCD x <- bh {2x, 2x+1}
  const int pj = ib >> 4;                         // 0..63
  const int tileA = 127 - pj, tileB = pj;
  const int nsA = tileA + 1, nsB = tileB + 1;     // nsA >= 65 > 4 always

  const unsigned short* Qp = Qbf + (size_t)bh * T * D;
  const unsigned short* Kp = Kbf + (size_t)bh * T * D;
  const unsigned short* Vp = Vt + (size_t)bh * D * T;

  auto run_phase = [&](int tile, int s0, int ns, int slot) {
    const int qidx = tile * 32 + lane31;
    const bf16x8 qf = *(const bf16x8*)(Qp + (size_t)qidx * D + 8 * h);
    float m = -1e30f, lsum = 0.f;       // first check always rescales (a=0)
    f32x16 acc = {};

    auto loadK = [&](int s) -> bf16x8 {
      return *(const bf16x8*)(Kp + (size_t)(s * 32 + lane31) * D + 8 * h);
    };
    auto mask_diag = [&](f32x16& s16, int k0) {
#pragma unroll
      for (int r = 0; r < 16; ++r) {
        const int key = k0 + (r & 3) + 8 * (r >> 2) + 4 * h;
        if (key > qidx) s16[r] = -1e30f;
      }
    };
    auto lmax16 = [&](const f32x16& s16) -> float {
      const float t0 = fmaxf(fmaxf(s16[0], s16[1]), s16[2]);
      const float t1 = fmaxf(fmaxf(s16[3], s16[4]), s16[5]);
      const float t2 = fmaxf(fmaxf(s16[6], s16[7]), s16[8]);
      const float t3 = fmaxf(fmaxf(s16[9], s16[10]), s16[11]);
      const float t4 = fmaxf(fmaxf(s16[12], s16[13]), s16[14]);
      return fmaxf(fmaxf(fmaxf(t0, t1), t2), fmaxf(fmaxf(t3, t4), s16[15]));
    };
    auto rescale_if = [&](float lm) {
      if (!__all(lm <= m + 8.f)) {      // rare (deferred max), wave-uniform
        const float tm = fmaxf(lm, __shfl_xor(lm, 32, 64));
        const float mn = fmaxf(m, tm);
        const float alpha = EXP2F(m - mn);
        lsum *= alpha;
#pragma unroll
        for (int j = 0; j < 8; ++j) acc[j] *= alpha;
        m = mn;
      }
    };
    auto expsum = [&](f32x16& s16) {
#pragma unroll
      for (int r = 0; r < 16; ++r) s16[r] = EXP2F(s16[r] - m);
      lsum += ((s16[0] + s16[1]) + (s16[2] + s16[3])) +
              ((s16[4] + s16[5]) + (s16[6] + s16[7])) +
              ((s16[8] + s16[9]) + (s16[10] + s16[11])) +
              ((s16[12] + s16[13]) + (s16[14] + s16[15]));
    };
    auto pv = [&](const f32x16& s16, const u16x4& v0, const u16x4& v1,
                  const u16x4& v2, const u16x4& v3) {
      union PF { bf16x8 v; uint32_t u[4]; } pa, pb;
      pa.u[0] = cvt_pk_bf16(s16[0], s16[1]);
      pa.u[1] = cvt_pk_bf16(s16[2], s16[3]);
      pa.u[2] = cvt_pk_bf16(s16[4], s16[5]);
      pa.u[3] = cvt_pk_bf16(s16[6], s16[7]);
      pb.u[0] = cvt_pk_bf16(s16[8], s16[9]);
      pb.u[1] = cvt_pk_bf16(s16[10], s16[11]);
      pb.u[2] = cvt_pk_bf16(s16[12], s16[13]);
      pb.u[3] = cvt_pk_bf16(s16[14], s16[15]);
      union VF { bf16x8 v; u16x4 q4[2]; } va, vb;
      va.q4[0] = v0; va.q4[1] = v1;     // keys k0+0..15  (slot fn = P's)
      vb.q4[0] = v2; vb.q4[1] = v3;     // keys k0+16..31
      __builtin_amdgcn_s_setprio(1);
      acc = __builtin_amdgcn_mfma_f32_32x32x16_bf16(va.v, pa.v, acc, 0, 0, 0);
      acc = __builtin_amdgcn_mfma_f32_32x32x16_bf16(vb.v, pb.v, acc, 0, 0, 0);
      __builtin_amdgcn_s_setprio(0);
    };

    int s = s0;
#pragma unroll 1
    for (; s + 4 < ns; s += 8) {        // two steps per iter: s and s+4
      const unsigned short* vba = Vp + (size_t)dv * T + s * 32 + 4 * h;
      const unsigned short* vbb = vba + 128;          // (s+4)*32
      const bf16x8 kfa = loadK(s);
      const u16x4 va0 = *(const u16x4*)(vba);
      const u16x4 va1 = *(const u16x4*)(vba + 8);
      const u16x4 va2 = *(const u16x4*)(vba + 16);
      const u16x4 va3 = *(const u16x4*)(vba + 24);
      const bf16x8 kfb = loadK(s + 4);
      const u16x4 vb0 = *(const u16x4*)(vbb);
      const u16x4 vb1 = *(const u16x4*)(vbb + 8);
      const u16x4 vb2 = *(const u16x4*)(vbb + 16);
      const u16x4 vb3 = *(const u16x4*)(vbb + 24);

      f32x16 sa = {}, sb = {};
      __builtin_amdgcn_s_setprio(1);
      sa = __builtin_amdgcn_mfma_f32_32x32x16_bf16(kfa, qf, sa, 0, 0, 0);
      sb = __builtin_amdgcn_mfma_f32_32x32x16_bf16(kfb, qf, sb, 0, 0, 0);
      __builtin_amdgcn_s_setprio(0);

      if (s == tile) mask_diag(sa, s * 32);
      if (s + 4 == tile) mask_diag(sb, (s + 4) * 32);

      rescale_if(fmaxf(lmax16(sa), lmax16(sb)));
      expsum(sa);
      expsum(sb);
      pv(sa, va0, va1, va2, va3);
      pv(sb, vb0, vb1, vb2, vb3);
    }
    if (s < ns) {                       // leftover single step
      const unsigned short* vba = Vp + (size_t)dv * T + s * 32 + 4 * h;
      const bf16x8 kfa = loadK(s);
      const u16x4 va0 = *(const u16x4*)(vba);
      const u16x4 va1 = *(const u16x4*)(vba + 8);
      const u16x4 va2 = *(const u16x4*)(vba + 16);
      const u16x4 va3 = *(const u16x4*)(vba + 24);
      f32x16 sa = {};
      __builtin_amdgcn_s_setprio(1);
      sa = __builtin_amdgcn_mfma_f32_32x32x16_bf16(kfa, qf, sa, 0, 0, 0);
      __builtin_amdgcn_s_setprio(0);
      if (s == tile) mask_diag(sa, s * 32);
      rescale_if(lmax16(sa));
      expsum(sa);
      pv(sa, va0, va1, va2, va3);
    }

    lsum += __shfl_xor(lsum, 32, 64);   // lane pair holds same q
    Pm[slot][w][lane31] = m;
    Pl[slot][w][lane31] = lsum;
#pragma unroll
    for (int j = 0; j < 8; ++j) {
      const int dj = (j & 3) + 8 * (j >> 2) + 4 * h;
      Po[slot][w][lane31][dj] = acc[j];
    }
  };

  // phase A: steps i = w, w+4, ... while i < nsA
  run_phase(tileA, w, nsA, 0);
  // phase B: continue combined list; first B step = i_end - nsA
  const int cA = (nsA - w + 3) >> 2;
  const int sB0 = w + 4 * cA - nsA;
  run_phase(tileB, sB0, nsB, 1);

  __syncthreads();

  if (w < 2) {                          // wave 0 -> tile A, wave 1 -> tile B
    const int tile = (w == 0) ? tileA : tileB;
    const int qidx = tile * 32 + lane31;
    float M = Pm[w][0][lane31];
#pragma unroll
    for (int p = 1; p < 4; ++p) M = fmaxf(M, Pm[w][p][lane31]);
    float L = 0.f, od[8] = {};
#pragma unroll
    for (int p = 0; p < 4; ++p) {
      const float wsc = EXP2F(Pm[w][p][lane31] - M);  // empty slots -> 0
      L = fmaf(Pl[w][p][lane31], wsc, L);
#pragma unroll
      for (int j = 0; j < 8; ++j) {
        const int dj = (j & 3) + 8 * (j >> 2) + 4 * h;
        od[j] = fmaf(Po[w][p][lane31][dj], wsc, od[j]);
      }
    }
    const float inv = 1.f / L;
    float* base = att + ((size_t)bh * T + qidx) * D;
    *(float4*)(base + 4 * h) =
        make_float4(od[0] * inv, od[1] * inv, od[2] * inv, od[3] * inv);
    *(float4*)(base + 8 + 4 * h) =
        make_float4(od[4] * inv, od[5] * inv, od[6] * inv, od[7] * inv);
  }
}

// ---------------------------------------------------------------------------
// Kernel 3: output projection + bias (fp32, unchanged).
// ---------------------------------------------------------------------------
__global__ __launch_bounds__(256) void out_proj(
    const float* __restrict__ att, const float* __restrict__ Wp,
    const float* __restrict__ bp, float* __restrict__ out) {
  __shared__ float As[128][68];
  __shared__ float Bs[128][68];
  const int tid = threadIdx.x;
  const int t0 = blockIdx.x * 64;
  const int c0 = blockIdx.y * 64;

  for (int f = tid; f < 2048; f += 256) {
    const int mm = f & 63;
    const int cp = (f >> 6) << 2;
    const int tr = t0 + mm;
    const int b = tr >> 12, t = tr & (T - 1);
    const int h = cp >> 4, d0 = cp & 15;
    const float4 v = *(const float4*)(att + (((size_t)b * H + h) * T + t) * D + d0);
    As[cp + 0][mm] = v.x; As[cp + 1][mm] = v.y; As[cp + 2][mm] = v.z; As[cp + 3][mm] = v.w;
  }
  const float4* wsrc = (const float4*)(Wp + (size_t)c0 * C);
  for (int f = tid; f < 2048; f += 256) {
    const float4 v = wsrc[f];
    const int n = f >> 5, k = (f & 31) << 2;
    Bs[k + 0][n] = v.x; Bs[k + 1][n] = v.y; Bs[k + 2][n] = v.z; Bs[k + 3][n] = v.w;
  }
  __syncthreads();

  const int tx = tid & 15, ty = tid >> 4;
  float acc[4][4] = {};
#pragma unroll 8
  for (int k = 0; k < 128; ++k) {
    const float4 a = *(const float4*)&As[k][ty * 4];
    const float4 b = *(const float4*)&Bs[k][tx * 4];
    const float av[4] = {a.x, a.y, a.z, a.w};
    const float bv[4] = {b.x, b.y, b.z, b.w};
#pragma unroll
    for (int i = 0; i < 4; ++i)
#pragma unroll
      for (int j = 0; j < 4; ++j) acc[i][j] = fmaf(av[i], bv[j], acc[i][j]);
  }

  const float4 bias = *(const float4*)(bp + c0 + tx * 4);
#pragma unroll
  for (int i = 0; i < 4; ++i) {
    const int tr = t0 + ty * 4 + i;
    const float4 v = make_float4(acc[i][0] + bias.x, acc[i][1] + bias.y,
                                 acc[i][2] + bias.z, acc[i][3] + bias.w);
    *(float4*)(out + (size_t)tr * C + c0 + tx * 4) = v;
  }
}

}  // namespace

extern "C" void kernel_launch(void* const* d_in, const int* in_sizes, int n_in,
                              void* d_out, int out_size, void* d_ws, size_t ws_size,
                              hipStream_t stream) {
  // setup_inputs order: x, Wk, Wq, Wv, Wp, bp
  const float* x  = (const float*)d_in[0];
  const float* Wk = (const float*)d_in[1];
  const float* Wq = (const float*)d_in[2];
  const float* Wv = (const float*)d_in[3];
  const float* Wp = (const float*)d_in[4];
  const float* bp = (const float*)d_in[5];

  float* att = (float*)d_ws;                             // 4 MiB fp32
  unsigned short* Qbf = (unsigned short*)(att + PLANE);  // 2 MiB bf16
  unsigned short* Kbf = Qbf + PLANE;                     // 2 MiB
  unsigned short* Vtb = Kbf + PLANE;                     // 2 MiB (10 MiB ws)

  qkv_proj<<<dim3(128, 6), 256, 0, stream>>>(x, Wq, Wk, Wv, Qbf, Kbf, Vtb);
  attn_fwd<<<dim3(1024), 256, 0, stream>>>(Qbf, Kbf, Vtb, att);
  out_proj<<<dim3(128, 2), 256, 0, stream>>>(att, Wp, bp, (float*)d_out);
}